// Round 8
// baseline (413.035 us; speedup 1.0000x reference)
//
#include <hip/hip_runtime.h>
#include <hip/hip_bf16.h>
#include <math.h>

#define B_ 4
#define T_ 2049      // keys = prompt + 2048
#define TB 2048
#define Q_ 801
#define H_ 16
#define HD 64
#define E_ 1024
#define MROWS (B_ * T_)   // 8196
#define MT_TILES 513      // ceil(8196/16)

typedef short short8 __attribute__((ext_vector_type(8)));
typedef float floatx4 __attribute__((ext_vector_type(4)));
typedef int int4v __attribute__((ext_vector_type(4)));

__device__ __forceinline__ ushort f2bf(float x) {
    unsigned u = __float_as_uint(x);
    unsigned r = (u + 0x7fffu + ((u >> 16) & 1u)) >> 16;
    return (ushort)r;
}
__device__ __forceinline__ float bf2f(ushort h) {
    return __uint_as_float(((unsigned)h) << 16);
}
__device__ __forceinline__ void gload16(const void* g, void* l) {
    __builtin_amdgcn_global_load_lds(
        (const __attribute__((address_space(1))) void*)g,
        (__attribute__((address_space(3))) void*)l, 16, 0, 0);
}
// pack (bf16(p), bf16(p - bf16(p))) into one dword: hi low16, lo high16
__device__ __forceinline__ unsigned packsplit(float p) {
    __hip_bfloat16 hb = __float2bfloat16(p);
    float lo = p - __bfloat162float(hb);
    float2 pr; pr.x = p; pr.y = lo;
    __hip_bfloat162 v2 = __float22bfloat162_rn(pr);
    union { __hip_bfloat162 b; unsigned u; } cv;
    cv.b = v2;
    return cv.u;
}

// ---------------- Kernel 1: proj50[r,c] = sum_i pe[r,i] * Wpos[c,i] --------
__global__ __launch_bounds__(256) void proj50_kernel(
    const float* __restrict__ pe, const float* __restrict__ Wpos,
    float* __restrict__ proj50) {
    __shared__ float pes[1024];
    const int r = blockIdx.x;        // 0..49
    const int t = threadIdx.x;       // 256
    for (int p = 0; p < 4; ++p) pes[t + p * 256] = pe[(size_t)r * 1024 + t + p * 256];
    __syncthreads();
    const int c = blockIdx.y * 256 + t;
    const float4* w4 = (const float4*)(Wpos + (size_t)c * 1024);
    float acc = 0.f;
    for (int i = 0; i < 256; ++i) {
        float4 wv = w4[i];
        acc = fmaf(pes[4 * i + 0], wv.x, acc);
        acc = fmaf(pes[4 * i + 1], wv.y, acc);
        acc = fmaf(pes[4 * i + 2], wv.z, acc);
        acc = fmaf(pes[4 * i + 3], wv.w, acc);
    }
    proj50[(size_t)r * 1024 + c] = acc;
}

// ---------------- split_kv: kv rows -> MFMA-A-frag-major bf16 hi/lo --------
// afrag line ((mt*32 + kc)*64 + lane)*8 holds A[mt*16 + (lane&15)]
// [kc*32 + (lane>>4)*8 + j], j=0..7.
__global__ __launch_bounds__(256) void split_kv_kernel(
    const float* __restrict__ x_b, const float* __restrict__ pe,
    const float* __restrict__ prompt,
    ushort* __restrict__ afhi, ushort* __restrict__ aflo) {
    const int mt = blockIdx.x;            // 0..512
    const int t = threadIdx.x;
    const int lane = t & 63, kq = t >> 6;
    const int row_in = lane & 15, quad = lane >> 4;
    int m = mt * 16 + row_in; if (m > MROWS - 1) m = MROWS - 1;
    const int b = m / T_, tt = m - b * T_;
    const float* src; const float* pesrc; float psc;
    if (tt == 0) { src = prompt; pesrc = pe; psc = 0.f; }
    else {
        src = x_b + ((size_t)b * TB + tt - 1) * 1024;
        pesrc = pe + (size_t)(tt - 1) * 1024;
        psc = 1.f;
    }
    #pragma unroll
    for (int rep = 0; rep < 8; ++rep) {
        int kc = rep * 4 + kq;
        int k0 = kc * 32 + quad * 8;
        float4 xa = *(const float4*)(src + k0);
        float4 xb2 = *(const float4*)(src + k0 + 4);
        float4 pa = *(const float4*)(pesrc + k0);
        float4 pb = *(const float4*)(pesrc + k0 + 4);
        float vv[8];
        vv[0] = fmaf(psc, pa.x, xa.x);  vv[1] = fmaf(psc, pa.y, xa.y);
        vv[2] = fmaf(psc, pa.z, xa.z);  vv[3] = fmaf(psc, pa.w, xa.w);
        vv[4] = fmaf(psc, pb.x, xb2.x); vv[5] = fmaf(psc, pb.y, xb2.y);
        vv[6] = fmaf(psc, pb.z, xb2.z); vv[7] = fmaf(psc, pb.w, xb2.w);
        union { ushort u[8]; short8 s; } hu, lu;
        #pragma unroll
        for (int j = 0; j < 8; ++j) {
            ushort h = f2bf(vv[j]);
            hu.u[j] = h;
            lu.u[j] = f2bf(vv[j] - bf2f(h));
        }
        size_t off = ((size_t)(mt * 32 + kc) * 64 + lane) * 8;
        *(short8*)(afhi + off) = hu.s;
        *(short8*)(aflo + off) = lu.s;
    }
}

// ---------------- split_w: [Wk; Wv] rows -> frag-major bf16 hi/lo ----------
__global__ __launch_bounds__(256) void split_w_kernel(
    const float* __restrict__ Wk, const float* __restrict__ Wv,
    ushort* __restrict__ wfhi, ushort* __restrict__ wflo) {
    const int nt = blockIdx.x;            // 0..127 (concat K rows then V rows)
    const int t = threadIdx.x;
    const int lane = t & 63, kq = t >> 6;
    const int row_in = lane & 15, quad = lane >> 4;
    const int n = nt * 16 + row_in;       // 0..2047
    const float* src = (n < 1024) ? Wk + (size_t)n * 1024
                                  : Wv + (size_t)(n - 1024) * 1024;
    #pragma unroll
    for (int rep = 0; rep < 8; ++rep) {
        int kc = rep * 4 + kq;
        int k0 = kc * 32 + quad * 8;
        float4 xa = *(const float4*)(src + k0);
        float4 xb2 = *(const float4*)(src + k0 + 4);
        float vv[8] = {xa.x, xa.y, xa.z, xa.w, xb2.x, xb2.y, xb2.z, xb2.w};
        union { ushort u[8]; short8 s; } hu, lu;
        #pragma unroll
        for (int j = 0; j < 8; ++j) {
            ushort h = f2bf(vv[j]);
            hu.u[j] = h;
            lu.u[j] = f2bf(vv[j] - bf2f(h));
        }
        size_t off = ((size_t)(nt * 32 + kc) * 64 + lane) * 8;
        *(short8*)(wfhi + off) = hu.s;
        *(short8*)(wflo + off) = lu.s;
    }
}

// ---------------- Kernel 2: barrier-free LDS-free MFMA K/V GEMM ------------
// Both operands loaded directly from frag-major global layouts; no LDS, no
// __syncthreads — compiler free to pipeline loads across the K loop.
// K cols (n<1024): 3 planes -> khi/klo; V cols: 2 planes -> vbuf fp32.
__global__ __launch_bounds__(256) void kv_mfma_kernel(
    const ushort* __restrict__ afhi, const ushort* __restrict__ aflo,
    const ushort* __restrict__ wfhi, const ushort* __restrict__ wflo,
    ushort* __restrict__ khi, ushort* __restrict__ klo,
    float* __restrict__ vout) {

    const int t = threadIdx.x, lane = t & 63, w = t >> 6;
    const int wm = w >> 1, wn = w & 1;
    const int m0 = blockIdx.y * 128, n0 = blockIdx.x * 128;
    const bool isK = (n0 < 1024);
    const size_t lb = (size_t)lane * 8;

    const ushort* ah_p[4]; const ushort* al_p[4];
    const ushort* bh_p[4]; const ushort* bl_p[4];
    #pragma unroll
    for (int i = 0; i < 4; ++i) {
        size_t mt = (size_t)(blockIdx.y * 8 + wm * 4 + i);
        ah_p[i] = afhi + mt * 16384 + lb;
        al_p[i] = aflo + mt * 16384 + lb;
        size_t nt = (size_t)(blockIdx.x * 8 + wn * 4 + i);
        bh_p[i] = wfhi + nt * 16384 + lb;
        bl_p[i] = wflo + nt * 16384 + lb;
    }

    floatx4 acc[4][4];
    #pragma unroll
    for (int i = 0; i < 4; ++i)
        #pragma unroll
        for (int j = 0; j < 4; ++j)
            acc[i][j] = (floatx4){0.f, 0.f, 0.f, 0.f};

    if (isK) {
        for (int kc = 0; kc < 32; ++kc) {
            const int ko = kc * 512;
            short8 ah[4], al[4], bh[4], bl[4];
            #pragma unroll
            for (int i = 0; i < 4; ++i) {
                ah[i] = *(const short8*)(ah_p[i] + ko);
                al[i] = *(const short8*)(al_p[i] + ko);
                bh[i] = *(const short8*)(bh_p[i] + ko);
                bl[i] = *(const short8*)(bl_p[i] + ko);
            }
            #pragma unroll
            for (int i = 0; i < 4; ++i)
                #pragma unroll
                for (int j = 0; j < 4; ++j) {
                    acc[i][j] = __builtin_amdgcn_mfma_f32_16x16x32_bf16(ah[i], bh[j], acc[i][j], 0, 0, 0);
                    acc[i][j] = __builtin_amdgcn_mfma_f32_16x16x32_bf16(ah[i], bl[j], acc[i][j], 0, 0, 0);
                    acc[i][j] = __builtin_amdgcn_mfma_f32_16x16x32_bf16(al[i], bh[j], acc[i][j], 0, 0, 0);
                }
        }
    } else {
        for (int kc = 0; kc < 32; ++kc) {
            const int ko = kc * 512;
            short8 ah[4], bh[4], bl[4];
            #pragma unroll
            for (int i = 0; i < 4; ++i) {
                ah[i] = *(const short8*)(ah_p[i] + ko);
                bh[i] = *(const short8*)(bh_p[i] + ko);
                bl[i] = *(const short8*)(bl_p[i] + ko);
            }
            #pragma unroll
            for (int i = 0; i < 4; ++i)
                #pragma unroll
                for (int j = 0; j < 4; ++j) {
                    acc[i][j] = __builtin_amdgcn_mfma_f32_16x16x32_bf16(ah[i], bh[j], acc[i][j], 0, 0, 0);
                    acc[i][j] = __builtin_amdgcn_mfma_f32_16x16x32_bf16(ah[i], bl[j], acc[i][j], 0, 0, 0);
                }
        }
    }

    // epilogue: C layout col = lane&15, row = (lane>>4)*4 + reg
    const int frow = lane & 15, foct = lane >> 4;
    const int ncol = (n0 & 1023) + wn * 64 + frow;
    #pragma unroll
    for (int i = 0; i < 4; ++i) {
        #pragma unroll
        for (int r = 0; r < 4; ++r) {
            int row = m0 + wm * 64 + i * 16 + foct * 4 + r;
            if (row < MROWS) {
                if (isK) {
                    #pragma unroll
                    for (int j = 0; j < 4; ++j) {
                        float v = acc[i][j][r];
                        ushort hv = f2bf(v);
                        ushort lv = f2bf(v - bf2f(hv));
                        khi[(size_t)row * 1024 + ncol + j * 16] = hv;
                        klo[(size_t)row * 1024 + ncol + j * 16] = lv;
                    }
                } else {
                    #pragma unroll
                    for (int j = 0; j < 4; ++j)
                        vout[(size_t)row * 1024 + ncol + j * 16] = acc[i][j][r];
                }
            }
        }
    }
}

// ---------------- vprep: V fp32 -> V^T fragment-major bf16 (coalesced) -----
__global__ __launch_bounds__(256) void vprep_kernel(
    const float* __restrict__ vbuf, ushort* __restrict__ vfrag) {
    __shared__ float vs[32][65];
    const int kc = blockIdx.x, h = blockIdx.y, b = blockIdx.z;
    const int t = threadIdx.x;
    {
        const int key = t >> 3, ds = (t & 7) * 8;
        int kidx = kc * 32 + key;
        if (kidx > 2048) kidx = 2048;
        const float* src = vbuf + ((size_t)(b * T_ + kidx)) * 1024 + h * 64 + ds;
        float4 a = *(const float4*)src;
        float4 c = *(const float4*)(src + 4);
        vs[key][ds + 0] = a.x; vs[key][ds + 1] = a.y;
        vs[key][ds + 2] = a.z; vs[key][ds + 3] = a.w;
        vs[key][ds + 4] = c.x; vs[key][ds + 5] = c.y;
        vs[key][ds + 6] = c.z; vs[key][ds + 7] = c.w;
    }
    __syncthreads();
    const int lane = t & 63, df = t >> 6;
    const int fr = lane & 15, qd = lane >> 4;
    const int dim = df * 16 + fr;
    union { ushort u[8]; short8 v; } tmp;
    #pragma unroll
    for (int j = 0; j < 8; ++j) tmp.u[j] = f2bf(vs[qd * 8 + j][dim]);
    short8* dst = (short8*)(vfrag + ((size_t)(((b * 16 + h) * 65 + kc) * 4 + df) * 64 + lane) * 8);
    *dst = tmp.v;
}

// ---------------- Kernel 3: MFMA flash attention (unchanged from R7) -------
__global__ __launch_bounds__(256, 3) void attn_mfma_kernel(
    const float* __restrict__ debug, const float* __restrict__ proj50,
    const ushort* __restrict__ khi, const ushort* __restrict__ klo,
    const ushort* __restrict__ vfrag,
    const float* __restrict__ gates, float* __restrict__ out) {

    __shared__ __align__(16) ushort Ksh[16 * 512];       // idx = kg*4+dc*2+pl
    __shared__ __align__(16) unsigned Psh[4 * 32 * 68];  // per-wave [32 q][68]

    const int t = threadIdx.x, lane = t & 63, w = t >> 6;   // 4 waves
    const int frow = lane & 15, quad = lane >> 4;
    const int h = blockIdx.y, b = blockIdx.z;
    const int qwave = blockIdx.x * 128 + w * 32;

    short8 qh[2][2], ql[2][2];
    #pragma unroll
    for (int sub = 0; sub < 2; ++sub) {
        int qrow = qwave + sub * 16 + frow; if (qrow > Q_ - 1) qrow = Q_ - 1;
        int idx = (qrow * 50) / Q_;
        const float* dsrc = debug + (((size_t)(b * H_ + h)) * Q_ + qrow) * HD;
        const float* psrc = proj50 + (size_t)idx * 1024 + h * HD;
        #pragma unroll
        for (int dc = 0; dc < 2; ++dc) {
            int d0 = dc * 32 + quad * 8;
            union { ushort u[8]; short8 v; } hh, ll;
            #pragma unroll
            for (int j = 0; j < 8; ++j) {
                float v = (dsrc[d0 + j] + psrc[d0 + j]) * 0.125f;
                ushort hv = f2bf(v);
                hh.u[j] = hv;
                ll.u[j] = f2bf(v - bf2f(hv));
            }
            qh[sub][dc] = hh.v; ql[sub][dc] = ll.v;
        }
    }

    const short8 ones = {(short)0x3F80, (short)0x3F80, (short)0x3F80, (short)0x3F80,
                         (short)0x3F80, (short)0x3F80, (short)0x3F80, (short)0x3F80};

    floatx4 oacc[2][4];
    #pragma unroll
    for (int sub = 0; sub < 2; ++sub)
        #pragma unroll
        for (int d = 0; d < 4; ++d) oacc[sub][d] = (floatx4){0.f, 0.f, 0.f, 0.f};
    floatx4 lacc[2];
    lacc[0] = (floatx4){0.f, 0.f, 0.f, 0.f};
    lacc[1] = (floatx4){0.f, 0.f, 0.f, 0.f};

    unsigned* Pw = &Psh[w * 32 * 68];
    const size_t bT = (size_t)b * T_;
    const size_t vbh = (size_t)(b * 16 + h) * 65;

    for (int t0 = 0; t0 < 2112; t0 += 64) {     // 33 tiles
        short8 vreg[2][4];
        #pragma unroll
        for (int kc = 0; kc < 2; ++kc) {
            int kcg = (t0 >> 5) + kc; if (kcg > 64) kcg = 64;
            const ushort* vsrc = vfrag + ((vbh + kcg) * 4) * 512 + lane * 8;
            #pragma unroll
            for (int df = 0; df < 4; ++df)
                vreg[kc][df] = *(const short8*)(vsrc + df * 512);
        }

        __syncthreads();
        {
            int key = t0 + w * 16 + frow; if (key > 2048) key = 2048;
            const size_t rowoff = (bT + key) * 1024 + h * 64 + quad * 8;
            #pragma unroll
            for (int s = 0; s < 4; ++s) {
                int dc = s >> 1, pl = s & 1;
                const ushort* src = (pl ? klo : khi) + rowoff + dc * 32;
                gload16(src, &Ksh[(w * 4 + s) * 512]);
            }
        }
        __syncthreads();

        floatx4 sacc[2][4];
        #pragma unroll
        for (int kg = 0; kg < 4; ++kg) {
            sacc[0][kg] = (floatx4){0.f, 0.f, 0.f, 0.f};
            sacc[1][kg] = (floatx4){0.f, 0.f, 0.f, 0.f};
            #pragma unroll
            for (int dc = 0; dc < 2; ++dc) {
                short8 kh = *(const short8*)&Ksh[(kg * 4 + dc * 2 + 0) * 512 + lane * 8];
                short8 kl = *(const short8*)&Ksh[(kg * 4 + dc * 2 + 1) * 512 + lane * 8];
                #pragma unroll
                for (int sub = 0; sub < 2; ++sub) {
                    sacc[sub][kg] = __builtin_amdgcn_mfma_f32_16x16x32_bf16(qh[sub][dc], kh, sacc[sub][kg], 0, 0, 0);
                    sacc[sub][kg] = __builtin_amdgcn_mfma_f32_16x16x32_bf16(qh[sub][dc], kl, sacc[sub][kg], 0, 0, 0);
                    sacc[sub][kg] = __builtin_amdgcn_mfma_f32_16x16x32_bf16(ql[sub][dc], kh, sacc[sub][kg], 0, 0, 0);
                }
            }
        }
        if (t0 == 2048) {
            #pragma unroll
            for (int kg = 0; kg < 4; ++kg) {
                bool inv = (kg * 16 + frow) > 0;
                #pragma unroll
                for (int sub = 0; sub < 2; ++sub)
                    #pragma unroll
                    for (int r = 0; r < 4; ++r)
                        sacc[sub][kg][r] = inv ? -1e30f : sacc[sub][kg][r];
            }
        }

        #pragma unroll
        for (int sub = 0; sub < 2; ++sub)
            #pragma unroll
            for (int kg = 0; kg < 4; ++kg)
                #pragma unroll
                for (int r = 0; r < 4; ++r)
                    Pw[(sub * 16 + quad * 4 + r) * 68 + kg * 16 + frow] =
                        packsplit(__expf(sacc[sub][kg][r]));

        #pragma unroll
        for (int kc = 0; kc < 2; ++kc) {
            #pragma unroll
            for (int sub = 0; sub < 2; ++sub) {
                const unsigned* pr = &Pw[(sub * 16 + frow) * 68 + kc * 32 + quad * 8];
                unsigned dwords[8];
                *(int4v*)&dwords[0] = *(const int4v*)pr;
                *(int4v*)&dwords[4] = *(const int4v*)(pr + 4);
                union { unsigned u[4]; short8 v; } phx, plx;
                #pragma unroll
                for (int m2 = 0; m2 < 4; ++m2) {
                    unsigned a = dwords[2 * m2], c = dwords[2 * m2 + 1];
                    phx.u[m2] = (a & 0xffffu) | (c << 16);
                    plx.u[m2] = (a >> 16) | (c & 0xffff0000u);
                }
                #pragma unroll
                for (int df = 0; df < 4; ++df) {
                    oacc[sub][df] = __builtin_amdgcn_mfma_f32_16x16x32_bf16(phx.v, vreg[kc][df], oacc[sub][df], 0, 0, 0);
                    oacc[sub][df] = __builtin_amdgcn_mfma_f32_16x16x32_bf16(plx.v, vreg[kc][df], oacc[sub][df], 0, 0, 0);
                }
                lacc[sub] = __builtin_amdgcn_mfma_f32_16x16x32_bf16(phx.v, ones, lacc[sub], 0, 0, 0);
                lacc[sub] = __builtin_amdgcn_mfma_f32_16x16x32_bf16(plx.v, ones, lacc[sub], 0, 0, 0);
            }
        }
    }

    const float g = gates[0];
    #pragma unroll
    for (int sub = 0; sub < 2; ++sub)
        #pragma unroll
        for (int r = 0; r < 4; ++r) {
            int q = qwave + sub * 16 + quad * 4 + r;
            if (q < Q_) {
                float s = g / lacc[sub][r];
                float* dst = out + ((size_t)b * Q_ + q) * E_ + h * HD + frow;
                #pragma unroll
                for (int df = 0; df < 4; ++df)
                    dst[df * 16] = oacc[sub][df][r] * s;
            }
        }
}

// ---------------- Fallback fp32 path (if workspace too small) --------------
#define SMK 36
__global__ __launch_bounds__(256) void kv_gemm_kernel(
    const float* __restrict__ x_b, const float* __restrict__ pe,
    const float* __restrict__ prompt,
    const float* __restrict__ Wk, const float* __restrict__ Wv,
    float* __restrict__ kout, float* __restrict__ vout) {

    __shared__ float As[64][SMK];
    __shared__ float Bks[64][SMK];
    __shared__ float Bvs[64][SMK];

    const int t = threadIdx.x;
    const int m0 = blockIdx.y * 64;
    const int n0 = blockIdx.x * 64;
    const int tx = t & 15, ty = t >> 4;
    const int rr = t >> 2;
    const int kp = (t & 3) * 8;

    int m = m0 + rr;
    if (m >= MROWS) m = 0;
    const int bb = m / T_;
    const int tt = m - bb * T_;
    const float* aptr; const float* peptr; float pesc;
    if (tt == 0) { aptr = prompt; peptr = pe; pesc = 0.f; }
    else {
        aptr = x_b + ((size_t)bb * TB + (tt - 1)) * 1024;
        peptr = pe + (size_t)(tt - 1) * 1024;
        pesc = 1.f;
    }
    const float* wkp = Wk + (size_t)(n0 + rr) * 1024;
    const float* wvp = Wv + (size_t)(n0 + rr) * 1024;

    float ck[4][4] = {{0.f}}, cv[4][4] = {{0.f}};

    for (int k0 = 0; k0 < 1024; k0 += 32) {
        __syncthreads();
        {
            float4 xa0 = *(const float4*)(aptr + k0 + kp);
            float4 xa1 = *(const float4*)(aptr + k0 + kp + 4);
            float4 pe0 = *(const float4*)(peptr + k0 + kp);
            float4 pe1 = *(const float4*)(peptr + k0 + kp + 4);
            xa0.x = fmaf(pesc, pe0.x, xa0.x);
            xa0.y = fmaf(pesc, pe0.y, xa0.y);
            xa0.z = fmaf(pesc, pe0.z, xa0.z);
            xa0.w = fmaf(pesc, pe0.w, xa0.w);
            xa1.x = fmaf(pesc, pe1.x, xa1.x);
            xa1.y = fmaf(pesc, pe1.y, xa1.y);
            xa1.z = fmaf(pesc, pe1.z, xa1.z);
            xa1.w = fmaf(pesc, pe1.w, xa1.w);
            *(float4*)&As[rr][kp]     = xa0;
            *(float4*)&As[rr][kp + 4] = xa1;
            *(float4*)&Bks[rr][kp]     = *(const float4*)(wkp + k0 + kp);
            *(float4*)&Bks[rr][kp + 4] = *(const float4*)(wkp + k0 + kp + 4);
            *(float4*)&Bvs[rr][kp]     = *(const float4*)(wvp + k0 + kp);
            *(float4*)&Bvs[rr][kp + 4] = *(const float4*)(wvp + k0 + kp + 4);
        }
        __syncthreads();
        for (int k4 = 0; k4 < 8; ++k4) {
            float4 a[4], bk[4], bv[4];
            #pragma unroll
            for (int i = 0; i < 4; ++i) a[i] = *(const float4*)&As[ty * 4 + i][k4 * 4];
            #pragma unroll
            for (int j = 0; j < 4; ++j) {
                bk[j] = *(const float4*)&Bks[tx * 4 + j][k4 * 4];
                bv[j] = *(const float4*)&Bvs[tx * 4 + j][k4 * 4];
            }
            #pragma unroll
            for (int i = 0; i < 4; ++i)
                #pragma unroll
                for (int j = 0; j < 4; ++j) {
                    ck[i][j] = fmaf(a[i].x, bk[j].x, ck[i][j]);
                    ck[i][j] = fmaf(a[i].y, bk[j].y, ck[i][j]);
                    ck[i][j] = fmaf(a[i].z, bk[j].z, ck[i][j]);
                    ck[i][j] = fmaf(a[i].w, bk[j].w, ck[i][j]);
                    cv[i][j] = fmaf(a[i].x, bv[j].x, cv[i][j]);
                    cv[i][j] = fmaf(a[i].y, bv[j].y, cv[i][j]);
                    cv[i][j] = fmaf(a[i].z, bv[j].z, cv[i][j]);
                    cv[i][j] = fmaf(a[i].w, bv[j].w, cv[i][j]);
                }
        }
    }

    #pragma unroll
    for (int i = 0; i < 4; ++i) {
        int mrow = m0 + ty * 4 + i;
        if (mrow < MROWS) {
            float4 kq, vq;
            kq.x = ck[i][0]; kq.y = ck[i][1]; kq.z = ck[i][2]; kq.w = ck[i][3];
            vq.x = cv[i][0]; vq.y = cv[i][1]; vq.z = cv[i][2]; vq.w = cv[i][3];
            *(float4*)(kout + (size_t)mrow * 1024 + n0 + tx * 4) = kq;
            *(float4*)(vout + (size_t)mrow * 1024 + n0 + tx * 4) = vq;
        }
    }
}

#define KSTR 68
__device__ __forceinline__ float dot16(const float (&q)[16], const float* kf) {
    float4 k0 = *(const float4*)(kf);
    float4 k1 = *(const float4*)(kf + 4);
    float4 k2 = *(const float4*)(kf + 8);
    float4 k3 = *(const float4*)(kf + 12);
    float p;
    p = q[0] * k0.x;
    p = fmaf(q[1], k0.y, p);  p = fmaf(q[2], k0.z, p);  p = fmaf(q[3], k0.w, p);
    p = fmaf(q[4], k1.x, p);  p = fmaf(q[5], k1.y, p);  p = fmaf(q[6], k1.z, p);  p = fmaf(q[7], k1.w, p);
    p = fmaf(q[8], k2.x, p);  p = fmaf(q[9], k2.y, p);  p = fmaf(q[10], k2.z, p); p = fmaf(q[11], k2.w, p);
    p = fmaf(q[12], k3.x, p); p = fmaf(q[13], k3.y, p); p = fmaf(q[14], k3.z, p); p = fmaf(q[15], k3.w, p);
    return p;
}
__device__ __forceinline__ void pv16(float (&o)[16], float pk, const float* vf) {
    float4 v0 = *(const float4*)(vf);
    float4 v1 = *(const float4*)(vf + 4);
    float4 v2 = *(const float4*)(vf + 8);
    float4 v3 = *(const float4*)(vf + 12);
    o[0]  = fmaf(pk, v0.x, o[0]);  o[1]  = fmaf(pk, v0.y, o[1]);
    o[2]  = fmaf(pk, v0.z, o[2]);  o[3]  = fmaf(pk, v0.w, o[3]);
    o[4]  = fmaf(pk, v1.x, o[4]);  o[5]  = fmaf(pk, v1.y, o[5]);
    o[6]  = fmaf(pk, v1.z, o[6]);  o[7]  = fmaf(pk, v1.w, o[7]);
    o[8]  = fmaf(pk, v2.x, o[8]);  o[9]  = fmaf(pk, v2.y, o[9]);
    o[10] = fmaf(pk, v2.z, o[10]); o[11] = fmaf(pk, v2.w, o[11]);
    o[12] = fmaf(pk, v3.x, o[12]); o[13] = fmaf(pk, v3.y, o[13]);
    o[14] = fmaf(pk, v3.z, o[14]); o[15] = fmaf(pk, v3.w, o[15]);
}

__global__ __launch_bounds__(256) void attn_kernel(
    const float* __restrict__ debug, const float* __restrict__ proj50,
    const float* __restrict__ kmat, const float* __restrict__ vmat,
    const float* __restrict__ gates, float* __restrict__ out) {

    __shared__ float k_s[64][KSTR];
    __shared__ float v_s[64][KSTR];

    const int t = threadIdx.x;
    const int lane = t & 63;
    const int w = t >> 6;
    const int r = lane >> 2;
    const int g = lane & 3;
    const int qi = blockIdx.x * 64 + w * 16 + r;
    const int h = blockIdx.y, b = blockIdx.z;
    const bool valid = qi < Q_;

    float q[16], o[16];
    {
        int qq = valid ? qi : 0;
        int idx = (qq * 50) / Q_;
        const float* dsrc = debug + (((size_t)(b * H_ + h)) * Q_ + qq) * HD + g * 16;
        const float* psrc = proj50 + (size_t)idx * 1024 + h * HD + g * 16;
        #pragma unroll
        for (int j4 = 0; j4 < 4; ++j4) {
            float4 dv = *(const float4*)(dsrc + j4 * 4);
            float4 pv = *(const float4*)(psrc + j4 * 4);
            q[j4 * 4 + 0] = (dv.x + pv.x) * 0.125f;
            q[j4 * 4 + 1] = (dv.y + pv.y) * 0.125f;
            q[j4 * 4 + 2] = (dv.z + pv.z) * 0.125f;
            q[j4 * 4 + 3] = (dv.w + pv.w) * 0.125f;
        }
    }
    float mrun = -INFINITY, lrun = 0.f;
    #pragma unroll
    for (int j = 0; j < 16; ++j) o[j] = 0.f;

    const int srow = t >> 2;
    const int scol = (t & 3) * 16;
    const float* kbase = kmat + ((size_t)b * T_) * E_ + h * HD + scol;
    const float* vbase = vmat + ((size_t)b * T_) * E_ + h * HD + scol;

    for (int t0 = 0; t0 < 2048; t0 += 64) {
        __syncthreads();
        {
            const float* kr = kbase + (size_t)(t0 + srow) * E_;
            const float* vr = vbase + (size_t)(t0 + srow) * E_;
            #pragma unroll
            for (int j4 = 0; j4 < 4; ++j4) {
                *(float4*)&k_s[srow][scol + j4 * 4] = *(const float4*)(kr + j4 * 4);
                *(float4*)&v_s[srow][scol + j4 * 4] = *(const float4*)(vr + j4 * 4);
            }
        }
        __syncthreads();
        #pragma unroll 1
        for (int kb = 0; kb < 64; kb += 16) {
            float sc[16];
            #pragma unroll
            for (int kk = 0; kk < 16; ++kk) {
                float p = dot16(q, &k_s[kb + kk][g * 16]);
                p += __shfl_xor(p, 1);
                p += __shfl_xor(p, 2);
                sc[kk] = p;
            }
            float mt = sc[0];
            #pragma unroll
            for (int kk = 1; kk < 16; ++kk) mt = fmaxf(mt, sc[kk]);
            float mn = fmaxf(mrun, mt);
            float al = __expf(mrun - mn);
            float ssum = 0.f;
            #pragma unroll
            for (int kk = 0; kk < 16; ++kk) { sc[kk] = __expf(sc[kk] - mn); ssum += sc[kk]; }
            mrun = mn;
            lrun = fmaf(lrun, al, ssum);
            #pragma unroll
            for (int j = 0; j < 16; ++j) o[j] *= al;
            #pragma unroll
            for (int kk = 0; kk < 16; ++kk) pv16(o, sc[kk], &v_s[kb + kk][g * 16]);
        }
    }
    {
        const float* kr = kmat + ((size_t)(b * T_ + 2048)) * E_ + h * HD + g * 16;
        const float* vr = vmat + ((size_t)(b * T_ + 2048)) * E_ + h * HD + g * 16;
        float p = dot16(q, kr);
        p += __shfl_xor(p, 1);
        p += __shfl_xor(p, 2);
        float mn = fmaxf(mrun, p);
        float al = __expf(mrun - mn);
        float pk = __expf(p - mn);
        lrun = fmaf(lrun, al, pk);
        #pragma unroll
        for (int j = 0; j < 16; ++j) o[j] *= al;
        pv16(o, pk, vr);
    }

    if (valid) {
        float s = gates[0] / lrun;
        float* dst = out + ((size_t)b * Q_ + qi) * E_ + h * HD + g * 16;
        #pragma unroll
        for (int j4 = 0; j4 < 4; ++j4) {
            float4 ov;
            ov.x = o[j4 * 4 + 0] * s;
            ov.y = o[j4 * 4 + 1] * s;
            ov.z = o[j4 * 4 + 2] * s;
            ov.w = o[j4 * 4 + 3] * s;
            *(float4*)(dst + j4 * 4) = ov;
        }
    }
}

extern "C" void kernel_launch(void* const* d_in, const int* in_sizes, int n_in,
                              void* d_out, int out_size, void* d_ws, size_t ws_size,
                              hipStream_t stream) {
    // inputs: x_a(0), x_b(1), debug(2), Wk(3), Wv(4), Wpos(5),
    //         prompt(6), gates(7), pe(8), full_b_step(9), full_a_step(10)
    const float* x_b = (const float*)d_in[1];
    const float* debug = (const float*)d_in[2];
    const float* Wk = (const float*)d_in[3];
    const float* Wv = (const float*)d_in[4];
    const float* Wpos = (const float*)d_in[5];
    const float* prompt = (const float*)d_in[6];
    const float* gates = (const float*)d_in[7];
    const float* pe = (const float*)d_in[8];
    float* out = (float*)d_out;

    char* ws = (char*)d_ws;
    const size_t KVH = (size_t)MROWS * 1024 * sizeof(ushort);      // 16,785,408
    const size_t KVF = (size_t)MROWS * 1024 * sizeof(float);       // 33,570,816
    const size_t AF  = (size_t)MT_TILES * 32 * 64 * 8 * sizeof(ushort);  // 16,809,984
    const size_t WF  = (size_t)128 * 32 * 64 * 8 * sizeof(ushort);       //  4,194,304
    const size_t P50 = 256 * 1024;

    float*  proj50 = (float*)ws;                   // 200 KB used, 256 KB reserved
    ushort* khi  = (ushort*)(ws + P50);
    ushort* klo  = (ushort*)(ws + P50 + KVH);
    float*  vbuf = (float*)(ws + P50 + 2 * KVH);
    ushort* afhi = (ushort*)(ws + P50 + 2 * KVH + KVF);
    ushort* aflo = (ushort*)(ws + P50 + 2 * KVH + KVF + AF);
    ushort* wfhi = (ushort*)(ws + P50 + 2 * KVH + KVF + 2 * AF);
    ushort* wflo = (ushort*)(ws + P50 + 2 * KVH + KVF + 2 * AF + WF);
    // vfrag (17.04 MB) aliases afhi+aflo (33.62 MB), both dead after kv_mfma
    ushort* vfrag = afhi;
    const size_t needed = P50 + 2 * KVH + KVF + 2 * AF + 2 * WF;  // 109,412,352

    proj50_kernel<<<dim3(50, 4), 256, 0, stream>>>(pe, Wpos, proj50);

    if (ws_size >= needed) {
        split_kv_kernel<<<dim3(MT_TILES), 256, 0, stream>>>(x_b, pe, prompt, afhi, aflo);
        split_w_kernel<<<dim3(128), 256, 0, stream>>>(Wk, Wv, wfhi, wflo);
        kv_mfma_kernel<<<dim3(16, 65), 256, 0, stream>>>(afhi, aflo, wfhi, wflo, khi, klo, vbuf);
        vprep_kernel<<<dim3(65, H_, B_), 256, 0, stream>>>(vbuf, vfrag);
        attn_mfma_kernel<<<dim3(7, H_, B_), 256, 0, stream>>>(
            debug, proj50, khi, klo, vfrag, gates, out);
    } else {
        float* kbuf = (float*)khi;   // fallback: fp32 K in khi+klo region (same size)
        kv_gemm_kernel<<<dim3(16, 129), 256, 0, stream>>>(x_b, pe, prompt, Wk, Wv, kbuf, vbuf);
        attn_kernel<<<dim3(13, H_, B_), 256, 0, stream>>>(debug, proj50, kbuf, vbuf, gates, out);
    }
}

// Round 9
// 369.874 us; speedup vs baseline: 1.1167x; 1.1167x over previous
//
#include <hip/hip_runtime.h>
#include <hip/hip_bf16.h>
#include <math.h>

#define B_ 4
#define T_ 2049      // keys = prompt + 2048
#define TB 2048
#define Q_ 801
#define H_ 16
#define HD 64
#define E_ 1024
#define MROWS (B_ * T_)   // 8196
#define MT_TILES 513      // ceil(8196/16)

typedef short short8 __attribute__((ext_vector_type(8)));
typedef float floatx4 __attribute__((ext_vector_type(4)));
typedef int int4v __attribute__((ext_vector_type(4)));

__device__ __forceinline__ ushort f2bf(float x) {
    unsigned u = __float_as_uint(x);
    unsigned r = (u + 0x7fffu + ((u >> 16) & 1u)) >> 16;
    return (ushort)r;
}
__device__ __forceinline__ float bf2f(ushort h) {
    return __uint_as_float(((unsigned)h) << 16);
}
__device__ __forceinline__ void gload16(const void* g, void* l) {
    __builtin_amdgcn_global_load_lds(
        (const __attribute__((address_space(1))) void*)g,
        (__attribute__((address_space(3))) void*)l, 16, 0, 0);
}
// pack (bf16(p), bf16(p - bf16(p))) into one dword: hi low16, lo high16
__device__ __forceinline__ unsigned packsplit(float p) {
    __hip_bfloat16 hb = __float2bfloat16(p);
    float lo = p - __bfloat162float(hb);
    float2 pr; pr.x = p; pr.y = lo;
    __hip_bfloat162 v2 = __float22bfloat162_rn(pr);
    union { __hip_bfloat162 b; unsigned u; } cv;
    cv.b = v2;
    return cv.u;
}

// ---------------- Kernel 1: proj50[r,c] = sum_i pe[r,i] * Wpos[c,i] --------
__global__ __launch_bounds__(256) void proj50_kernel(
    const float* __restrict__ pe, const float* __restrict__ Wpos,
    float* __restrict__ proj50) {
    __shared__ float pes[1024];
    const int r = blockIdx.x;        // 0..49
    const int t = threadIdx.x;       // 256
    for (int p = 0; p < 4; ++p) pes[t + p * 256] = pe[(size_t)r * 1024 + t + p * 256];
    __syncthreads();
    const int c = blockIdx.y * 256 + t;
    const float4* w4 = (const float4*)(Wpos + (size_t)c * 1024);
    float acc = 0.f;
    for (int i = 0; i < 256; ++i) {
        float4 wv = w4[i];
        acc = fmaf(pes[4 * i + 0], wv.x, acc);
        acc = fmaf(pes[4 * i + 1], wv.y, acc);
        acc = fmaf(pes[4 * i + 2], wv.z, acc);
        acc = fmaf(pes[4 * i + 3], wv.w, acc);
    }
    proj50[(size_t)r * 1024 + c] = acc;
}

// ---------------- split_kv: kv rows -> MFMA-A-frag-major bf16 hi/lo --------
__global__ __launch_bounds__(256) void split_kv_kernel(
    const float* __restrict__ x_b, const float* __restrict__ pe,
    const float* __restrict__ prompt,
    ushort* __restrict__ afhi, ushort* __restrict__ aflo) {
    const int mt = blockIdx.x;            // 0..512
    const int t = threadIdx.x;
    const int lane = t & 63, kq = t >> 6;
    const int row_in = lane & 15, quad = lane >> 4;
    int m = mt * 16 + row_in; if (m > MROWS - 1) m = MROWS - 1;
    const int b = m / T_, tt = m - b * T_;
    const float* src; const float* pesrc; float psc;
    if (tt == 0) { src = prompt; pesrc = pe; psc = 0.f; }
    else {
        src = x_b + ((size_t)b * TB + tt - 1) * 1024;
        pesrc = pe + (size_t)(tt - 1) * 1024;
        psc = 1.f;
    }
    #pragma unroll
    for (int rep = 0; rep < 8; ++rep) {
        int kc = rep * 4 + kq;
        int k0 = kc * 32 + quad * 8;
        float4 xa = *(const float4*)(src + k0);
        float4 xb2 = *(const float4*)(src + k0 + 4);
        float4 pa = *(const float4*)(pesrc + k0);
        float4 pb = *(const float4*)(pesrc + k0 + 4);
        float vv[8];
        vv[0] = fmaf(psc, pa.x, xa.x);  vv[1] = fmaf(psc, pa.y, xa.y);
        vv[2] = fmaf(psc, pa.z, xa.z);  vv[3] = fmaf(psc, pa.w, xa.w);
        vv[4] = fmaf(psc, pb.x, xb2.x); vv[5] = fmaf(psc, pb.y, xb2.y);
        vv[6] = fmaf(psc, pb.z, xb2.z); vv[7] = fmaf(psc, pb.w, xb2.w);
        union { ushort u[8]; short8 s; } hu, lu;
        #pragma unroll
        for (int j = 0; j < 8; ++j) {
            ushort h = f2bf(vv[j]);
            hu.u[j] = h;
            lu.u[j] = f2bf(vv[j] - bf2f(h));
        }
        size_t off = ((size_t)(mt * 32 + kc) * 64 + lane) * 8;
        *(short8*)(afhi + off) = hu.s;
        *(short8*)(aflo + off) = lu.s;
    }
}

// ---------------- split_w: [Wk; Wv] rows -> frag-major bf16 hi/lo ----------
__global__ __launch_bounds__(256) void split_w_kernel(
    const float* __restrict__ Wk, const float* __restrict__ Wv,
    ushort* __restrict__ wfhi, ushort* __restrict__ wflo) {
    const int nt = blockIdx.x;            // 0..127 (concat K rows then V rows)
    const int t = threadIdx.x;
    const int lane = t & 63, kq = t >> 6;
    const int row_in = lane & 15, quad = lane >> 4;
    const int n = nt * 16 + row_in;       // 0..2047
    const float* src = (n < 1024) ? Wk + (size_t)n * 1024
                                  : Wv + (size_t)(n - 1024) * 1024;
    #pragma unroll
    for (int rep = 0; rep < 8; ++rep) {
        int kc = rep * 4 + kq;
        int k0 = kc * 32 + quad * 8;
        float4 xa = *(const float4*)(src + k0);
        float4 xb2 = *(const float4*)(src + k0 + 4);
        float vv[8] = {xa.x, xa.y, xa.z, xa.w, xb2.x, xb2.y, xb2.z, xb2.w};
        union { ushort u[8]; short8 s; } hu, lu;
        #pragma unroll
        for (int j = 0; j < 8; ++j) {
            ushort h = f2bf(vv[j]);
            hu.u[j] = h;
            lu.u[j] = f2bf(vv[j] - bf2f(h));
        }
        size_t off = ((size_t)(nt * 32 + kc) * 64 + lane) * 8;
        *(short8*)(wfhi + off) = hu.s;
        *(short8*)(wflo + off) = lu.s;
    }
}

// ---------------- Kernel 2: barrier-free MFMA K/V GEMM, XCD-localized ------
// 1-D grid of 1040. XCD slot c = bid&7; y-groups assigned y ≡ c (mod 8)
// (tail group y=64 split 2-per-XCD) so each XCD's A slice (~4MB) stays L2-
// resident. Register double-buffer: chunk kc+1 loads in flight during kc's
// MFMAs. K cols: 3 planes -> khi/klo; V cols: 2 planes -> vout16 (bf16).
__global__ __launch_bounds__(256) void kv_mfma_kernel(
    const ushort* __restrict__ afhi, const ushort* __restrict__ aflo,
    const ushort* __restrict__ wfhi, const ushort* __restrict__ wflo,
    ushort* __restrict__ khi, ushort* __restrict__ klo,
    ushort* __restrict__ vout16) {

    const int t = threadIdx.x, lane = t & 63, w = t >> 6;
    const int wm = w >> 1, wn = w & 1;
    const int bid = blockIdx.x;
    const int c = bid & 7, jj2 = bid >> 3;
    int xx, yy;
    if (jj2 < 128) { yy = ((jj2 >> 4) << 3) + c; xx = jj2 & 15; }
    else           { yy = 64; xx = c * 2 + (jj2 - 128); }
    const int m0 = yy * 128, n0x = xx * 128;
    const bool isK = (xx < 8);
    const size_t lb = (size_t)lane * 8;

    const ushort* ah_p[4]; const ushort* al_p[4];
    const ushort* bh_p[4]; const ushort* bl_p[4];
    #pragma unroll
    for (int i = 0; i < 4; ++i) {
        size_t mt = (size_t)(yy * 8 + wm * 4 + i);
        ah_p[i] = afhi + mt * 16384 + lb;
        al_p[i] = aflo + mt * 16384 + lb;
        size_t nt = (size_t)(xx * 8 + wn * 4 + i);
        bh_p[i] = wfhi + nt * 16384 + lb;
        bl_p[i] = wflo + nt * 16384 + lb;
    }

    floatx4 acc[4][4];
    #pragma unroll
    for (int i = 0; i < 4; ++i)
        #pragma unroll
        for (int j = 0; j < 4; ++j)
            acc[i][j] = (floatx4){0.f, 0.f, 0.f, 0.f};

    if (isK) {
        short8 a0h[4], a0l[4], b0h[4], b0l[4];
        short8 a1h[4], a1l[4], b1h[4], b1l[4];
        #pragma unroll
        for (int i = 0; i < 4; ++i) {
            a0h[i] = *(const short8*)(ah_p[i]);
            a0l[i] = *(const short8*)(al_p[i]);
            b0h[i] = *(const short8*)(bh_p[i]);
            b0l[i] = *(const short8*)(bl_p[i]);
        }
        #pragma unroll 1
        for (int kc = 0; kc < 32; kc += 2) {
            {
                const int ko = (kc + 1) * 512;
                #pragma unroll
                for (int i = 0; i < 4; ++i) {
                    a1h[i] = *(const short8*)(ah_p[i] + ko);
                    a1l[i] = *(const short8*)(al_p[i] + ko);
                    b1h[i] = *(const short8*)(bh_p[i] + ko);
                    b1l[i] = *(const short8*)(bl_p[i] + ko);
                }
            }
            #pragma unroll
            for (int i = 0; i < 4; ++i)
                #pragma unroll
                for (int j = 0; j < 4; ++j) {
                    acc[i][j] = __builtin_amdgcn_mfma_f32_16x16x32_bf16(a0h[i], b0h[j], acc[i][j], 0, 0, 0);
                    acc[i][j] = __builtin_amdgcn_mfma_f32_16x16x32_bf16(a0h[i], b0l[j], acc[i][j], 0, 0, 0);
                    acc[i][j] = __builtin_amdgcn_mfma_f32_16x16x32_bf16(a0l[i], b0h[j], acc[i][j], 0, 0, 0);
                }
            if (kc + 2 < 32) {
                const int ko = (kc + 2) * 512;
                #pragma unroll
                for (int i = 0; i < 4; ++i) {
                    a0h[i] = *(const short8*)(ah_p[i] + ko);
                    a0l[i] = *(const short8*)(al_p[i] + ko);
                    b0h[i] = *(const short8*)(bh_p[i] + ko);
                    b0l[i] = *(const short8*)(bl_p[i] + ko);
                }
            }
            #pragma unroll
            for (int i = 0; i < 4; ++i)
                #pragma unroll
                for (int j = 0; j < 4; ++j) {
                    acc[i][j] = __builtin_amdgcn_mfma_f32_16x16x32_bf16(a1h[i], b1h[j], acc[i][j], 0, 0, 0);
                    acc[i][j] = __builtin_amdgcn_mfma_f32_16x16x32_bf16(a1h[i], b1l[j], acc[i][j], 0, 0, 0);
                    acc[i][j] = __builtin_amdgcn_mfma_f32_16x16x32_bf16(a1l[i], b1h[j], acc[i][j], 0, 0, 0);
                }
        }
    } else {
        short8 a0h[4], b0h[4], b0l[4];
        short8 a1h[4], b1h[4], b1l[4];
        #pragma unroll
        for (int i = 0; i < 4; ++i) {
            a0h[i] = *(const short8*)(ah_p[i]);
            b0h[i] = *(const short8*)(bh_p[i]);
            b0l[i] = *(const short8*)(bl_p[i]);
        }
        #pragma unroll 1
        for (int kc = 0; kc < 32; kc += 2) {
            {
                const int ko = (kc + 1) * 512;
                #pragma unroll
                for (int i = 0; i < 4; ++i) {
                    a1h[i] = *(const short8*)(ah_p[i] + ko);
                    b1h[i] = *(const short8*)(bh_p[i] + ko);
                    b1l[i] = *(const short8*)(bl_p[i] + ko);
                }
            }
            #pragma unroll
            for (int i = 0; i < 4; ++i)
                #pragma unroll
                for (int j = 0; j < 4; ++j) {
                    acc[i][j] = __builtin_amdgcn_mfma_f32_16x16x32_bf16(a0h[i], b0h[j], acc[i][j], 0, 0, 0);
                    acc[i][j] = __builtin_amdgcn_mfma_f32_16x16x32_bf16(a0h[i], b0l[j], acc[i][j], 0, 0, 0);
                }
            if (kc + 2 < 32) {
                const int ko = (kc + 2) * 512;
                #pragma unroll
                for (int i = 0; i < 4; ++i) {
                    a0h[i] = *(const short8*)(ah_p[i] + ko);
                    b0h[i] = *(const short8*)(bh_p[i] + ko);
                    b0l[i] = *(const short8*)(bl_p[i] + ko);
                }
            }
            #pragma unroll
            for (int i = 0; i < 4; ++i)
                #pragma unroll
                for (int j = 0; j < 4; ++j) {
                    acc[i][j] = __builtin_amdgcn_mfma_f32_16x16x32_bf16(a1h[i], b1h[j], acc[i][j], 0, 0, 0);
                    acc[i][j] = __builtin_amdgcn_mfma_f32_16x16x32_bf16(a1h[i], b1l[j], acc[i][j], 0, 0, 0);
                }
        }
    }

    // epilogue: C layout col = lane&15, row = (lane>>4)*4 + reg
    const int frow = lane & 15, foct = lane >> 4;
    const int ncol = (n0x & 1023) + wn * 64 + frow;
    #pragma unroll
    for (int i = 0; i < 4; ++i) {
        #pragma unroll
        for (int r = 0; r < 4; ++r) {
            int row = m0 + wm * 64 + i * 16 + foct * 4 + r;
            if (row < MROWS) {
                if (isK) {
                    #pragma unroll
                    for (int j = 0; j < 4; ++j) {
                        float v = acc[i][j][r];
                        ushort hv = f2bf(v);
                        ushort lv = f2bf(v - bf2f(hv));
                        khi[(size_t)row * 1024 + ncol + j * 16] = hv;
                        klo[(size_t)row * 1024 + ncol + j * 16] = lv;
                    }
                } else {
                    #pragma unroll
                    for (int j = 0; j < 4; ++j)
                        vout16[(size_t)row * 1024 + ncol + j * 16] = f2bf(acc[i][j][r]);
                }
            }
        }
    }
}

// ---------------- vprep: V bf16 rows -> V^T fragment-major (coalesced) -----
__global__ __launch_bounds__(256) void vprep_kernel(
    const ushort* __restrict__ vbuf16, ushort* __restrict__ vfrag) {
    __shared__ ushort vs[32][80];   // stride 80 ushorts = 160B (16B aligned)
    const int kc = blockIdx.x, h = blockIdx.y, b = blockIdx.z;
    const int t = threadIdx.x;
    {
        const int key = t >> 3, ds = (t & 7) * 8;
        int kidx = kc * 32 + key;
        if (kidx > 2048) kidx = 2048;
        const ushort* src = vbuf16 + ((size_t)(b * T_ + kidx)) * 1024 + h * 64 + ds;
        *(short8*)&vs[key][ds] = *(const short8*)src;
    }
    __syncthreads();
    const int lane = t & 63, df = t >> 6;
    const int fr = lane & 15, qd = lane >> 4;
    const int dim = df * 16 + fr;
    union { ushort u[8]; short8 v; } tmp;
    #pragma unroll
    for (int j = 0; j < 8; ++j) tmp.u[j] = vs[qd * 8 + j][dim];
    short8* dst = (short8*)(vfrag + ((size_t)(((b * 16 + h) * 65 + kc) * 4 + df) * 64 + lane) * 8);
    *dst = tmp.v;
}

// ---------------- Kernel 3: MFMA flash attention (unchanged from R8) -------
__global__ __launch_bounds__(256, 3) void attn_mfma_kernel(
    const float* __restrict__ debug, const float* __restrict__ proj50,
    const ushort* __restrict__ khi, const ushort* __restrict__ klo,
    const ushort* __restrict__ vfrag,
    const float* __restrict__ gates, float* __restrict__ out) {

    __shared__ __align__(16) ushort Ksh[16 * 512];       // idx = kg*4+dc*2+pl
    __shared__ __align__(16) unsigned Psh[4 * 32 * 68];  // per-wave [32 q][68]

    const int t = threadIdx.x, lane = t & 63, w = t >> 6;   // 4 waves
    const int frow = lane & 15, quad = lane >> 4;
    const int h = blockIdx.y, b = blockIdx.z;
    const int qwave = blockIdx.x * 128 + w * 32;

    short8 qh[2][2], ql[2][2];
    #pragma unroll
    for (int sub = 0; sub < 2; ++sub) {
        int qrow = qwave + sub * 16 + frow; if (qrow > Q_ - 1) qrow = Q_ - 1;
        int idx = (qrow * 50) / Q_;
        const float* dsrc = debug + (((size_t)(b * H_ + h)) * Q_ + qrow) * HD;
        const float* psrc = proj50 + (size_t)idx * 1024 + h * HD;
        #pragma unroll
        for (int dc = 0; dc < 2; ++dc) {
            int d0 = dc * 32 + quad * 8;
            union { ushort u[8]; short8 v; } hh, ll;
            #pragma unroll
            for (int j = 0; j < 8; ++j) {
                float v = (dsrc[d0 + j] + psrc[d0 + j]) * 0.125f;
                ushort hv = f2bf(v);
                hh.u[j] = hv;
                ll.u[j] = f2bf(v - bf2f(hv));
            }
            qh[sub][dc] = hh.v; ql[sub][dc] = ll.v;
        }
    }

    const short8 ones = {(short)0x3F80, (short)0x3F80, (short)0x3F80, (short)0x3F80,
                         (short)0x3F80, (short)0x3F80, (short)0x3F80, (short)0x3F80};

    floatx4 oacc[2][4];
    #pragma unroll
    for (int sub = 0; sub < 2; ++sub)
        #pragma unroll
        for (int d = 0; d < 4; ++d) oacc[sub][d] = (floatx4){0.f, 0.f, 0.f, 0.f};
    floatx4 lacc[2];
    lacc[0] = (floatx4){0.f, 0.f, 0.f, 0.f};
    lacc[1] = (floatx4){0.f, 0.f, 0.f, 0.f};

    unsigned* Pw = &Psh[w * 32 * 68];
    const size_t bT = (size_t)b * T_;
    const size_t vbh = (size_t)(b * 16 + h) * 65;

    for (int t0 = 0; t0 < 2112; t0 += 64) {     // 33 tiles
        short8 vreg[2][4];
        #pragma unroll
        for (int kc = 0; kc < 2; ++kc) {
            int kcg = (t0 >> 5) + kc; if (kcg > 64) kcg = 64;
            const ushort* vsrc = vfrag + ((vbh + kcg) * 4) * 512 + lane * 8;
            #pragma unroll
            for (int df = 0; df < 4; ++df)
                vreg[kc][df] = *(const short8*)(vsrc + df * 512);
        }

        __syncthreads();
        {
            int key = t0 + w * 16 + frow; if (key > 2048) key = 2048;
            const size_t rowoff = (bT + key) * 1024 + h * 64 + quad * 8;
            #pragma unroll
            for (int s = 0; s < 4; ++s) {
                int dc = s >> 1, pl = s & 1;
                const ushort* src = (pl ? klo : khi) + rowoff + dc * 32;
                gload16(src, &Ksh[(w * 4 + s) * 512]);
            }
        }
        __syncthreads();

        floatx4 sacc[2][4];
        #pragma unroll
        for (int kg = 0; kg < 4; ++kg) {
            sacc[0][kg] = (floatx4){0.f, 0.f, 0.f, 0.f};
            sacc[1][kg] = (floatx4){0.f, 0.f, 0.f, 0.f};
            #pragma unroll
            for (int dc = 0; dc < 2; ++dc) {
                short8 kh = *(const short8*)&Ksh[(kg * 4 + dc * 2 + 0) * 512 + lane * 8];
                short8 kl = *(const short8*)&Ksh[(kg * 4 + dc * 2 + 1) * 512 + lane * 8];
                #pragma unroll
                for (int sub = 0; sub < 2; ++sub) {
                    sacc[sub][kg] = __builtin_amdgcn_mfma_f32_16x16x32_bf16(qh[sub][dc], kh, sacc[sub][kg], 0, 0, 0);
                    sacc[sub][kg] = __builtin_amdgcn_mfma_f32_16x16x32_bf16(qh[sub][dc], kl, sacc[sub][kg], 0, 0, 0);
                    sacc[sub][kg] = __builtin_amdgcn_mfma_f32_16x16x32_bf16(ql[sub][dc], kh, sacc[sub][kg], 0, 0, 0);
                }
            }
        }
        if (t0 == 2048) {
            #pragma unroll
            for (int kg = 0; kg < 4; ++kg) {
                bool inv = (kg * 16 + frow) > 0;
                #pragma unroll
                for (int sub = 0; sub < 2; ++sub)
                    #pragma unroll
                    for (int r = 0; r < 4; ++r)
                        sacc[sub][kg][r] = inv ? -1e30f : sacc[sub][kg][r];
            }
        }

        #pragma unroll
        for (int sub = 0; sub < 2; ++sub)
            #pragma unroll
            for (int kg = 0; kg < 4; ++kg)
                #pragma unroll
                for (int r = 0; r < 4; ++r)
                    Pw[(sub * 16 + quad * 4 + r) * 68 + kg * 16 + frow] =
                        packsplit(__expf(sacc[sub][kg][r]));

        #pragma unroll
        for (int kc = 0; kc < 2; ++kc) {
            #pragma unroll
            for (int sub = 0; sub < 2; ++sub) {
                const unsigned* pr = &Pw[(sub * 16 + frow) * 68 + kc * 32 + quad * 8];
                unsigned dwords[8];
                *(int4v*)&dwords[0] = *(const int4v*)pr;
                *(int4v*)&dwords[4] = *(const int4v*)(pr + 4);
                union { unsigned u[4]; short8 v; } phx, plx;
                #pragma unroll
                for (int m2 = 0; m2 < 4; ++m2) {
                    unsigned a = dwords[2 * m2], cc = dwords[2 * m2 + 1];
                    phx.u[m2] = (a & 0xffffu) | (cc << 16);
                    plx.u[m2] = (a >> 16) | (cc & 0xffff0000u);
                }
                #pragma unroll
                for (int df = 0; df < 4; ++df) {
                    oacc[sub][df] = __builtin_amdgcn_mfma_f32_16x16x32_bf16(phx.v, vreg[kc][df], oacc[sub][df], 0, 0, 0);
                    oacc[sub][df] = __builtin_amdgcn_mfma_f32_16x16x32_bf16(plx.v, vreg[kc][df], oacc[sub][df], 0, 0, 0);
                }
                lacc[sub] = __builtin_amdgcn_mfma_f32_16x16x32_bf16(phx.v, ones, lacc[sub], 0, 0, 0);
                lacc[sub] = __builtin_amdgcn_mfma_f32_16x16x32_bf16(plx.v, ones, lacc[sub], 0, 0, 0);
            }
        }
    }

    const float g = gates[0];
    #pragma unroll
    for (int sub = 0; sub < 2; ++sub)
        #pragma unroll
        for (int r = 0; r < 4; ++r) {
            int q = qwave + sub * 16 + quad * 4 + r;
            if (q < Q_) {
                float s = g / lacc[sub][r];
                float* dst = out + ((size_t)b * Q_ + q) * E_ + h * HD + frow;
                #pragma unroll
                for (int df = 0; df < 4; ++df)
                    dst[df * 16] = oacc[sub][df][r] * s;
            }
        }
}

// ---------------- Fallback fp32 path (if workspace too small) --------------
#define SMK 36
__global__ __launch_bounds__(256) void kv_gemm_kernel(
    const float* __restrict__ x_b, const float* __restrict__ pe,
    const float* __restrict__ prompt,
    const float* __restrict__ Wk, const float* __restrict__ Wv,
    float* __restrict__ kout, float* __restrict__ vout) {

    __shared__ float As[64][SMK];
    __shared__ float Bks[64][SMK];
    __shared__ float Bvs[64][SMK];

    const int t = threadIdx.x;
    const int m0 = blockIdx.y * 64;
    const int n0 = blockIdx.x * 64;
    const int tx = t & 15, ty = t >> 4;
    const int rr = t >> 2;
    const int kp = (t & 3) * 8;

    int m = m0 + rr;
    if (m >= MROWS) m = 0;
    const int bb = m / T_;
    const int tt = m - bb * T_;
    const float* aptr; const float* peptr; float pesc;
    if (tt == 0) { aptr = prompt; peptr = pe; pesc = 0.f; }
    else {
        aptr = x_b + ((size_t)bb * TB + (tt - 1)) * 1024;
        peptr = pe + (size_t)(tt - 1) * 1024;
        pesc = 1.f;
    }
    const float* wkp = Wk + (size_t)(n0 + rr) * 1024;
    const float* wvp = Wv + (size_t)(n0 + rr) * 1024;

    float ck[4][4] = {{0.f}}, cv[4][4] = {{0.f}};

    for (int k0 = 0; k0 < 1024; k0 += 32) {
        __syncthreads();
        {
            float4 xa0 = *(const float4*)(aptr + k0 + kp);
            float4 xa1 = *(const float4*)(aptr + k0 + kp + 4);
            float4 pe0 = *(const float4*)(peptr + k0 + kp);
            float4 pe1 = *(const float4*)(peptr + k0 + kp + 4);
            xa0.x = fmaf(pesc, pe0.x, xa0.x);
            xa0.y = fmaf(pesc, pe0.y, xa0.y);
            xa0.z = fmaf(pesc, pe0.z, xa0.z);
            xa0.w = fmaf(pesc, pe0.w, xa0.w);
            xa1.x = fmaf(pesc, pe1.x, xa1.x);
            xa1.y = fmaf(pesc, pe1.y, xa1.y);
            xa1.z = fmaf(pesc, pe1.z, xa1.z);
            xa1.w = fmaf(pesc, pe1.w, xa1.w);
            *(float4*)&As[rr][kp]     = xa0;
            *(float4*)&As[rr][kp + 4] = xa1;
            *(float4*)&Bks[rr][kp]     = *(const float4*)(wkp + k0 + kp);
            *(float4*)&Bks[rr][kp + 4] = *(const float4*)(wkp + k0 + kp + 4);
            *(float4*)&Bvs[rr][kp]     = *(const float4*)(wvp + k0 + kp);
            *(float4*)&Bvs[rr][kp + 4] = *(const float4*)(wvp + k0 + kp + 4);
        }
        __syncthreads();
        for (int k4 = 0; k4 < 8; ++k4) {
            float4 a[4], bk[4], bv[4];
            #pragma unroll
            for (int i = 0; i < 4; ++i) a[i] = *(const float4*)&As[ty * 4 + i][k4 * 4];
            #pragma unroll
            for (int j = 0; j < 4; ++j) {
                bk[j] = *(const float4*)&Bks[tx * 4 + j][k4 * 4];
                bv[j] = *(const float4*)&Bvs[tx * 4 + j][k4 * 4];
            }
            #pragma unroll
            for (int i = 0; i < 4; ++i)
                #pragma unroll
                for (int j = 0; j < 4; ++j) {
                    ck[i][j] = fmaf(a[i].x, bk[j].x, ck[i][j]);
                    ck[i][j] = fmaf(a[i].y, bk[j].y, ck[i][j]);
                    ck[i][j] = fmaf(a[i].z, bk[j].z, ck[i][j]);
                    ck[i][j] = fmaf(a[i].w, bk[j].w, ck[i][j]);
                    cv[i][j] = fmaf(a[i].x, bv[j].x, cv[i][j]);
                    cv[i][j] = fmaf(a[i].y, bv[j].y, cv[i][j]);
                    cv[i][j] = fmaf(a[i].z, bv[j].z, cv[i][j]);
                    cv[i][j] = fmaf(a[i].w, bv[j].w, cv[i][j]);
                }
        }
    }

    #pragma unroll
    for (int i = 0; i < 4; ++i) {
        int mrow = m0 + ty * 4 + i;
        if (mrow < MROWS) {
            float4 kq, vq;
            kq.x = ck[i][0]; kq.y = ck[i][1]; kq.z = ck[i][2]; kq.w = ck[i][3];
            vq.x = cv[i][0]; vq.y = cv[i][1]; vq.z = cv[i][2]; vq.w = cv[i][3];
            *(float4*)(kout + (size_t)mrow * 1024 + n0 + tx * 4) = kq;
            *(float4*)(vout + (size_t)mrow * 1024 + n0 + tx * 4) = vq;
        }
    }
}

#define KSTR 68
__device__ __forceinline__ float dot16(const float (&q)[16], const float* kf) {
    float4 k0 = *(const float4*)(kf);
    float4 k1 = *(const float4*)(kf + 4);
    float4 k2 = *(const float4*)(kf + 8);
    float4 k3 = *(const float4*)(kf + 12);
    float p;
    p = q[0] * k0.x;
    p = fmaf(q[1], k0.y, p);  p = fmaf(q[2], k0.z, p);  p = fmaf(q[3], k0.w, p);
    p = fmaf(q[4], k1.x, p);  p = fmaf(q[5], k1.y, p);  p = fmaf(q[6], k1.z, p);  p = fmaf(q[7], k1.w, p);
    p = fmaf(q[8], k2.x, p);  p = fmaf(q[9], k2.y, p);  p = fmaf(q[10], k2.z, p); p = fmaf(q[11], k2.w, p);
    p = fmaf(q[12], k3.x, p); p = fmaf(q[13], k3.y, p); p = fmaf(q[14], k3.z, p); p = fmaf(q[15], k3.w, p);
    return p;
}
__device__ __forceinline__ void pv16(float (&o)[16], float pk, const float* vf) {
    float4 v0 = *(const float4*)(vf);
    float4 v1 = *(const float4*)(vf + 4);
    float4 v2 = *(const float4*)(vf + 8);
    float4 v3 = *(const float4*)(vf + 12);
    o[0]  = fmaf(pk, v0.x, o[0]);  o[1]  = fmaf(pk, v0.y, o[1]);
    o[2]  = fmaf(pk, v0.z, o[2]);  o[3]  = fmaf(pk, v0.w, o[3]);
    o[4]  = fmaf(pk, v1.x, o[4]);  o[5]  = fmaf(pk, v1.y, o[5]);
    o[6]  = fmaf(pk, v1.z, o[6]);  o[7]  = fmaf(pk, v1.w, o[7]);
    o[8]  = fmaf(pk, v2.x, o[8]);  o[9]  = fmaf(pk, v2.y, o[9]);
    o[10] = fmaf(pk, v2.z, o[10]); o[11] = fmaf(pk, v2.w, o[11]);
    o[12] = fmaf(pk, v3.x, o[12]); o[13] = fmaf(pk, v3.y, o[13]);
    o[14] = fmaf(pk, v3.z, o[14]); o[15] = fmaf(pk, v3.w, o[15]);
}

__global__ __launch_bounds__(256) void attn_kernel(
    const float* __restrict__ debug, const float* __restrict__ proj50,
    const float* __restrict__ kmat, const float* __restrict__ vmat,
    const float* __restrict__ gates, float* __restrict__ out) {

    __shared__ float k_s[64][KSTR];
    __shared__ float v_s[64][KSTR];

    const int t = threadIdx.x;
    const int lane = t & 63;
    const int w = t >> 6;
    const int r = lane >> 2;
    const int g = lane & 3;
    const int qi = blockIdx.x * 64 + w * 16 + r;
    const int h = blockIdx.y, b = blockIdx.z;
    const bool valid = qi < Q_;

    float q[16], o[16];
    {
        int qq = valid ? qi : 0;
        int idx = (qq * 50) / Q_;
        const float* dsrc = debug + (((size_t)(b * H_ + h)) * Q_ + qq) * HD + g * 16;
        const float* psrc = proj50 + (size_t)idx * 1024 + h * HD + g * 16;
        #pragma unroll
        for (int j4 = 0; j4 < 4; ++j4) {
            float4 dv = *(const float4*)(dsrc + j4 * 4);
            float4 pv = *(const float4*)(psrc + j4 * 4);
            q[j4 * 4 + 0] = (dv.x + pv.x) * 0.125f;
            q[j4 * 4 + 1] = (dv.y + pv.y) * 0.125f;
            q[j4 * 4 + 2] = (dv.z + pv.z) * 0.125f;
            q[j4 * 4 + 3] = (dv.w + pv.w) * 0.125f;
        }
    }
    float mrun = -INFINITY, lrun = 0.f;
    #pragma unroll
    for (int j = 0; j < 16; ++j) o[j] = 0.f;

    const int srow = t >> 2;
    const int scol = (t & 3) * 16;
    const float* kbase = kmat + ((size_t)b * T_) * E_ + h * HD + scol;
    const float* vbase = vmat + ((size_t)b * T_) * E_ + h * HD + scol;

    for (int t0 = 0; t0 < 2048; t0 += 64) {
        __syncthreads();
        {
            const float* kr = kbase + (size_t)(t0 + srow) * E_;
            const float* vr = vbase + (size_t)(t0 + srow) * E_;
            #pragma unroll
            for (int j4 = 0; j4 < 4; ++j4) {
                *(float4*)&k_s[srow][scol + j4 * 4] = *(const float4*)(kr + j4 * 4);
                *(float4*)&v_s[srow][scol + j4 * 4] = *(const float4*)(vr + j4 * 4);
            }
        }
        __syncthreads();
        #pragma unroll 1
        for (int kb = 0; kb < 64; kb += 16) {
            float sc[16];
            #pragma unroll
            for (int kk = 0; kk < 16; ++kk) {
                float p = dot16(q, &k_s[kb + kk][g * 16]);
                p += __shfl_xor(p, 1);
                p += __shfl_xor(p, 2);
                sc[kk] = p;
            }
            float mt = sc[0];
            #pragma unroll
            for (int kk = 1; kk < 16; ++kk) mt = fmaxf(mt, sc[kk]);
            float mn = fmaxf(mrun, mt);
            float al = __expf(mrun - mn);
            float ssum = 0.f;
            #pragma unroll
            for (int kk = 0; kk < 16; ++kk) { sc[kk] = __expf(sc[kk] - mn); ssum += sc[kk]; }
            mrun = mn;
            lrun = fmaf(lrun, al, ssum);
            #pragma unroll
            for (int j = 0; j < 16; ++j) o[j] *= al;
            #pragma unroll
            for (int kk = 0; kk < 16; ++kk) pv16(o, sc[kk], &v_s[kb + kk][g * 16]);
        }
    }
    {
        const float* kr = kmat + ((size_t)(b * T_ + 2048)) * E_ + h * HD + g * 16;
        const float* vr = vmat + ((size_t)(b * T_ + 2048)) * E_ + h * HD + g * 16;
        float p = dot16(q, kr);
        p += __shfl_xor(p, 1);
        p += __shfl_xor(p, 2);
        float mn = fmaxf(mrun, p);
        float al = __expf(mrun - mn);
        float pk = __expf(p - mn);
        lrun = fmaf(lrun, al, pk);
        #pragma unroll
        for (int j = 0; j < 16; ++j) o[j] *= al;
        pv16(o, pk, vr);
    }

    if (valid) {
        float s = gates[0] / lrun;
        float* dst = out + ((size_t)b * Q_ + qi) * E_ + h * HD + g * 16;
        #pragma unroll
        for (int j4 = 0; j4 < 4; ++j4) {
            float4 ov;
            ov.x = o[j4 * 4 + 0] * s;
            ov.y = o[j4 * 4 + 1] * s;
            ov.z = o[j4 * 4 + 2] * s;
            ov.w = o[j4 * 4 + 3] * s;
            *(float4*)(dst + j4 * 4) = ov;
        }
    }
}

extern "C" void kernel_launch(void* const* d_in, const int* in_sizes, int n_in,
                              void* d_out, int out_size, void* d_ws, size_t ws_size,
                              hipStream_t stream) {
    // inputs: x_a(0), x_b(1), debug(2), Wk(3), Wv(4), Wpos(5),
    //         prompt(6), gates(7), pe(8), full_b_step(9), full_a_step(10)
    const float* x_b = (const float*)d_in[1];
    const float* debug = (const float*)d_in[2];
    const float* Wk = (const float*)d_in[3];
    const float* Wv = (const float*)d_in[4];
    const float* Wpos = (const float*)d_in[5];
    const float* prompt = (const float*)d_in[6];
    const float* gates = (const float*)d_in[7];
    const float* pe = (const float*)d_in[8];
    float* out = (float*)d_out;

    char* ws = (char*)d_ws;
    const size_t KVH = (size_t)MROWS * 1024 * sizeof(ushort);      // 16,785,408
    const size_t KVF = (size_t)MROWS * 1024 * sizeof(float);       // 33,570,816
    const size_t AF  = (size_t)MT_TILES * 32 * 64 * 8 * sizeof(ushort);  // 16,809,984
    const size_t WF  = (size_t)128 * 32 * 64 * 8 * sizeof(ushort);       //  4,194,304
    const size_t P50 = 256 * 1024;

    float*  proj50 = (float*)ws;                   // 200 KB used, 256 KB reserved
    ushort* khi  = (ushort*)(ws + P50);
    ushort* klo  = (ushort*)(ws + P50 + KVH);
    float*  vbuf = (float*)(ws + P50 + 2 * KVH);   // fp32 region (fallback); main
    ushort* vbuf16 = (ushort*)vbuf;                // path uses first half as bf16
    ushort* afhi = (ushort*)(ws + P50 + 2 * KVH + KVF);
    ushort* aflo = (ushort*)(ws + P50 + 2 * KVH + KVF + AF);
    ushort* wfhi = (ushort*)(ws + P50 + 2 * KVH + KVF + 2 * AF);
    ushort* wflo = (ushort*)(ws + P50 + 2 * KVH + KVF + 2 * AF + WF);
    // vfrag (17.04 MB) aliases afhi+aflo (33.62 MB), both dead after kv_mfma
    ushort* vfrag = afhi;
    const size_t needed = P50 + 2 * KVH + KVF + 2 * AF + 2 * WF;  // 109,412,352

    proj50_kernel<<<dim3(50, 4), 256, 0, stream>>>(pe, Wpos, proj50);

    if (ws_size >= needed) {
        split_kv_kernel<<<dim3(MT_TILES), 256, 0, stream>>>(x_b, pe, prompt, afhi, aflo);
        split_w_kernel<<<dim3(128), 256, 0, stream>>>(Wk, Wv, wfhi, wflo);
        kv_mfma_kernel<<<dim3(1040), 256, 0, stream>>>(afhi, aflo, wfhi, wflo, khi, klo, vbuf16);
        vprep_kernel<<<dim3(65, H_, B_), 256, 0, stream>>>(vbuf16, vfrag);
        attn_mfma_kernel<<<dim3(7, H_, B_), 256, 0, stream>>>(
            debug, proj50, khi, klo, vfrag, gates, out);
    } else {
        float* kbuf = (float*)khi;   // fallback: fp32 K in khi+klo region (same size)
        kv_gemm_kernel<<<dim3(16, 129), 256, 0, stream>>>(x_b, pe, prompt, Wk, Wv, kbuf, vbuf);
        attn_kernel<<<dim3(13, H_, B_), 256, 0, stream>>>(debug, proj50, kbuf, vbuf, gates, out);
    }
}